// Round 3
// baseline (3961.842 us; speedup 1.0000x reference)
//
#include <hip/hip_runtime.h>
#include <math.h>

// Neural Turing Machine forward, fully fused persistent kernel.
// Grid: 256 blocks x 1024 threads; each block owns G=2 batch elements and
// runs all T=64 steps with state in LDS. No inter-block communication.
//
// R2 change: 512 -> 1024 threads/block (8 -> 16 waves/CU) to hide L2 load
// latency in the weight-streaming GEMMs (R1 counters: VALUBusy 42%,
// occupancy 24%, HBM ~0 -> latency-bound).
// z-GEMM: 4-way k-split (quarter q = tid>>8 handles 10 Wk rows + 64 Wr rows),
// float4 weight loads + float4 LDS h reads; partials zp[4] summed in gate
// phase. Head GEMM: 4-way k-split (64-row chains). Addressing: 512-way slot
// parallelism, upper half duplicates (same-value LDS writes are benign;
// reductions read non-dup waves only).

#define NSLOT  256
#define MU     32
#define MPAD   33      // +1 pad: avoids 32-bank conflicts on M rows
#define TSTEPS 64
#define EPSF   1e-8f

__device__ __forceinline__ float sigf(float x){ return 1.0f/(1.0f + expf(-x)); }
__device__ __forceinline__ float softplusf_(float x){ return fmaxf(x,0.0f) + log1pf(expf(-fabsf(x))); }

__device__ __forceinline__ float wred_sum(float v){
  #pragma unroll
  for (int m = 32; m >= 1; m >>= 1) v += __shfl_xor(v, m, 64);
  return v;
}
__device__ __forceinline__ float wred_max(float v){
  #pragma unroll
  for (int m = 32; m >= 1; m >>= 1) v = fmaxf(v, __shfl_xor(v, m, 64));
  return v;
}

struct __align__(16) Smem {
  float M[2][NSLOT][MPAD];   // memory, padded rows              67.6 KB
  float zp[4][2][1024];      // z partials [quarter][g][col]     32   KB
  float h[2][256];           // 16B-aligned (offset 100352)
  float c[2][256];
  float hob[2][140];         // [read ho(38) | write wo(102)]
  float xcat[2][40];         // [x(8) | R(32)]
  float wr[2][NSLOT];        // read weights state
  float ww[2][NSLOT];        // write weights state
  float wg[2][2][NSLOT];     // shift-conv scratch [head][g][slot]
  float k[2][2][MU];         // key buffer [head][g][m]
  float E[2][MU];
  float A[2][MU];
  float R[2][MU];
  float hpart[4][2][140];    // head GEMM partials [quarter][g][col]
  float rpart[2][16][32];    // read-vector partials [g][chunk][m]
  float red[3][16];          // per-site reduction buffers (16 waves)
};

// Block-level reduction over batch-slot g2a. 16 waves: waves 0-3 g2=0 dup0,
// 4-7 g2=0 dup1 (identical values), 8-11 g2=1 dup0, 12-15 g2=1 dup1.
// Sum/max reads only the dup0 waves of the caller's g2a. Caller passes a
// DISTINCT red buffer per site (no leading barrier needed). ALL 1024 threads
// must call.
__device__ __forceinline__ float grp_red_sum(float v, float* red, int wave, int lane, int g2a){
  v = wred_sum(v);
  if (lane == 0) red[wave] = v;
  __syncthreads();
  const int b = g2a*8;
  return red[b] + red[b+1] + red[b+2] + red[b+3];
}
__device__ __forceinline__ float grp_red_max(float v, float* red, int wave, int lane, int g2a){
  v = wred_max(v);
  if (lane == 0) red[wave] = v;
  __syncthreads();
  const int b = g2a*8;
  return fmaxf(fmaxf(red[b], red[b+1]), fmaxf(red[b+2], red[b+3]));
}

// NTM addressing for one head. ho: 38 raw outputs for batch-slot g2a. wst:
// previous weights (updated in place). Mg: this slot's memory base.
// head = 0 (read) / 1 (write) selects private k/wg buffers. Duplicate threads
// (waves 4-7, 12-15) recompute identical values; same-value LDS writes are
// benign, and wst reads are separated from wst writes by internal barriers.
__device__ void address_head(int g2a, int n2, int wave, int lane, int head,
                             const float* ho, float* wst, const float* Mg,
                             Smem& s)
{
  // per-head scalars, computed redundantly by every thread (LDS broadcast reads)
  float beta  = softplusf_(ho[32]);
  float gg    = sigf(ho[33]);
  float r0 = ho[34], r1 = ho[35], r2 = ho[36];
  float m3 = fmaxf(r0, fmaxf(r1, r2));
  float e0 = expf(r0-m3), e1 = expf(r1-m3), e2 = expf(r2-m3);
  float inv3 = 1.0f/(e0+e1+e2);
  float s0 = e0*inv3, s1 = e1*inv3, s2 = e2*inv3;
  float gamma = 1.0f + softplusf_(ho[37]);

  float* kbuf  = &s.k[head][g2a][0];
  float* wgbuf = &s.wg[head][g2a][0];

  if (n2 < MU) kbuf[n2] = tanhf(ho[n2]);
  __syncthreads();

  float kn = 0.0f;
  #pragma unroll
  for (int m = 0; m < MU; ++m){ float kv = kbuf[m]; kn = fmaf(kv, kv, kn); }
  kn = sqrtf(kn);

  // cosine similarity for this thread's slot n2
  const float* Mr = Mg + n2*MPAD;
  float dot = 0.0f, mm = 0.0f;
  #pragma unroll
  for (int m = 0; m < MU; ++m){ float mv = Mr[m]; dot = fmaf(mv, kbuf[m], dot); mm = fmaf(mv, mv, mm); }
  float sim = dot / (sqrtf(mm)*kn + EPSF);

  // content softmax over 256 slots
  float bs = beta * sim;
  float mx = grp_red_max(bs, s.red[0], wave, lane, g2a);
  float ex = expf(bs - mx);
  float sm = grp_red_sum(ex, s.red[1], wave, lane, g2a);
  float wc = ex / sm;

  // interpolate with previous weights, publish for shift conv
  float wgv = fmaf(gg, wc, (1.0f - gg)*wst[n2]);
  wgbuf[n2] = wgv;
  __syncthreads();

  // circular shift conv: w_s[i] = s0*wg[i+1] + s1*wg[i] + s2*wg[i-1]
  float ws = s0*wgbuf[(n2+1)&255] + s1*wgbuf[n2] + s2*wgbuf[(n2-1)&255];

  // sharpen + normalize
  float wp = powf(ws, gamma);
  float sp = grp_red_sum(wp, s.red[2], wave, lane, g2a);
  wst[n2] = wp / (sp + EPSF);
}

__global__ __launch_bounds__(1024)
void ntm_fused(const float* __restrict__ X,
               const float* __restrict__ Wk,   const float* __restrict__ Wr,
               const float* __restrict__ Lb,
               const float* __restrict__ rW,   const float* __restrict__ rb,
               const float* __restrict__ wW,   const float* __restrict__ wb,
               const float* __restrict__ oW,   const float* __restrict__ ob,
               const float* __restrict__ rInit,
               const float* __restrict__ wrI,  const float* __restrict__ wwI,
               float* __restrict__ Y)
{
  __shared__ Smem s;

  const int tid  = threadIdx.x;
  const int q    = tid >> 8;        // quarter 0..3 (k-split index)
  const int n2   = tid & 255;       // unit / slot / column-group index
  const int wave = tid >> 6;        // 0..15
  const int lane = tid & 63;
  const int gh   = q & 1;           // batch slot for tid<512 phases
  const int g2a  = tid >> 9;        // batch slot for addressing (all threads)
  const int bB   = blockIdx.x * 2;  // first batch element of this block

  // ---------------- init state (512 threads; no internal barriers) ----------------
  if (tid < 512) {
    for (int m = 0; m < MU; ++m) s.M[gh][n2][m] = 1e-6f;
    s.h[gh][n2] = 0.0f;
    s.c[gh][n2] = 0.0f;
    if (n2 < MU) s.R[gh][n2] = tanhf(rInit[n2]);
    // initial weight softmaxes (serial per thread, init-only, broadcast reads)
    float mx = -1e30f;
    for (int i = 0; i < NSLOT; ++i) mx = fmaxf(mx, wrI[i]);
    float sm = 0.0f;
    for (int i = 0; i < NSLOT; ++i) sm += expf(wrI[i] - mx);
    s.wr[gh][n2] = expf(wrI[n2] - mx) / sm;
    mx = -1e30f;
    for (int i = 0; i < NSLOT; ++i) mx = fmaxf(mx, wwI[i]);
    sm = 0.0f;
    for (int i = 0; i < NSLOT; ++i) sm += expf(wwI[i] - mx);
    s.ww[gh][n2] = expf(wwI[n2] - mx) / sm;
  }
  __syncthreads();

  // ---------------- time loop ----------------
  for (int t = 0; t < TSTEPS; ++t) {
    // x_cat = [x(8) | R(32)] for both batch slots
    if (tid < 512 && n2 < 40) {
      s.xcat[gh][n2] = (n2 < 8) ? X[((bB + gh)*TSTEPS + t)*8 + n2]
                                : s.R[gh][n2 - 8];
    }
    __syncthreads();

    // ---- z = x_cat@Wk + h@Wr (+b in gate phase); 4-way k-split ----
    // quarter q: Wk rows 10q..10q+9, Wr rows 64q..64q+63.
    {
      const int c0 = n2 * 4;
      float a0x=0.f,a0y=0.f,a0z=0.f,a0w=0.f;   // g=0
      float a1x=0.f,a1y=0.f,a1z=0.f,a1w=0.f;   // g=1
      const int kb = 10*q;
      #pragma unroll
      for (int ii = 0; ii < 10; ++ii) {
        const int i = kb + ii;
        float4 w = *(const float4*)&Wk[i*1024 + c0];
        float x0 = s.xcat[0][i], x1 = s.xcat[1][i];
        a0x=fmaf(w.x,x0,a0x); a0y=fmaf(w.y,x0,a0y); a0z=fmaf(w.z,x0,a0z); a0w=fmaf(w.w,x0,a0w);
        a1x=fmaf(w.x,x1,a1x); a1y=fmaf(w.y,x1,a1y); a1z=fmaf(w.z,x1,a1z); a1w=fmaf(w.w,x1,a1w);
      }
      const int rb4 = 16*q;
      #pragma unroll 2
      for (int i4 = 0; i4 < 16; ++i4) {
        const int r = (rb4 + i4)*4;
        float4 h0 = *(const float4*)&s.h[0][r];
        float4 h1 = *(const float4*)&s.h[1][r];
        float4 w0 = *(const float4*)&Wr[(r+0)*1024 + c0];
        float4 w1 = *(const float4*)&Wr[(r+1)*1024 + c0];
        float4 w2 = *(const float4*)&Wr[(r+2)*1024 + c0];
        float4 w3 = *(const float4*)&Wr[(r+3)*1024 + c0];
        a0x=fmaf(w0.x,h0.x,a0x); a0y=fmaf(w0.y,h0.x,a0y); a0z=fmaf(w0.z,h0.x,a0z); a0w=fmaf(w0.w,h0.x,a0w);
        a1x=fmaf(w0.x,h1.x,a1x); a1y=fmaf(w0.y,h1.x,a1y); a1z=fmaf(w0.z,h1.x,a1z); a1w=fmaf(w0.w,h1.x,a1w);
        a0x=fmaf(w1.x,h0.y,a0x); a0y=fmaf(w1.y,h0.y,a0y); a0z=fmaf(w1.z,h0.y,a0z); a0w=fmaf(w1.w,h0.y,a0w);
        a1x=fmaf(w1.x,h1.y,a1x); a1y=fmaf(w1.y,h1.y,a1y); a1z=fmaf(w1.z,h1.y,a1z); a1w=fmaf(w1.w,h1.y,a1w);
        a0x=fmaf(w2.x,h0.z,a0x); a0y=fmaf(w2.y,h0.z,a0y); a0z=fmaf(w2.z,h0.z,a0z); a0w=fmaf(w2.w,h0.z,a0w);
        a1x=fmaf(w2.x,h1.z,a1x); a1y=fmaf(w2.y,h1.z,a1y); a1z=fmaf(w2.z,h1.z,a1z); a1w=fmaf(w2.w,h1.z,a1w);
        a0x=fmaf(w3.x,h0.w,a0x); a0y=fmaf(w3.y,h0.w,a0y); a0z=fmaf(w3.z,h0.w,a0z); a0w=fmaf(w3.w,h0.w,a0w);
        a1x=fmaf(w3.x,h1.w,a1x); a1y=fmaf(w3.y,h1.w,a1y); a1z=fmaf(w3.z,h1.w,a1z); a1w=fmaf(w3.w,h1.w,a1w);
      }
      *(float4*)&s.zp[q][0][c0] = make_float4(a0x,a0y,a0z,a0w);
      *(float4*)&s.zp[q][1][c0] = make_float4(a1x,a1y,a1z,a1w);
    }
    __syncthreads();

    // ---- LSTM gates (keras order i,f,g,o); Z==h since |h|<1<CLIP ----
    if (tid < 512) {
      float zi = s.zp[0][gh][n2      ]+s.zp[1][gh][n2      ]+s.zp[2][gh][n2      ]+s.zp[3][gh][n2      ] + Lb[n2      ];
      float zf = s.zp[0][gh][n2 + 256]+s.zp[1][gh][n2 + 256]+s.zp[2][gh][n2 + 256]+s.zp[3][gh][n2 + 256] + Lb[n2 + 256];
      float zg = s.zp[0][gh][n2 + 512]+s.zp[1][gh][n2 + 512]+s.zp[2][gh][n2 + 512]+s.zp[3][gh][n2 + 512] + Lb[n2 + 512];
      float zo = s.zp[0][gh][n2 + 768]+s.zp[1][gh][n2 + 768]+s.zp[2][gh][n2 + 768]+s.zp[3][gh][n2 + 768] + Lb[n2 + 768];
      float cn = sigf(zf)*s.c[gh][n2] + sigf(zi)*tanhf(zg);
      float hn = sigf(zo)*tanhf(cn);
      s.c[gh][n2] = cn;
      s.h[gh][n2] = hn;
    }
    __syncthreads();

    // ---- head outputs: ho = h @ [read_W | write_W]; 4-way k-split ----
    if (n2 < 140) {
      const float* Wp; int stride, cc;
      if (n2 < 38) { Wp = rW; stride = 38;  cc = n2; }
      else         { Wp = wW; stride = 102; cc = n2 - 38; }
      const int i0 = q * 64;
      float acc0 = 0.0f, acc1 = 0.0f;
      #pragma unroll 4
      for (int ii = 0; ii < 64; ++ii) {
        const int i = i0 + ii;
        float wv = Wp[i*stride + cc];
        acc0 = fmaf(wv, s.h[0][i], acc0);
        acc1 = fmaf(wv, s.h[1][i], acc1);
      }
      s.hpart[q][0][n2] = acc0;
      s.hpart[q][1][n2] = acc1;
    }
    __syncthreads();
    if (tid < 512 && n2 < 140) {
      float bias = (n2 < 38) ? rb[n2] : wb[n2 - 38];
      s.hob[gh][n2] = s.hpart[0][gh][n2] + s.hpart[1][gh][n2]
                    + s.hpart[2][gh][n2] + s.hpart[3][gh][n2] + bias;
    }
    __syncthreads();

    // erase / add vectors (write head raw outputs wo[38:70], wo[70:102])
    if (tid < 512 && n2 < MU) {
      s.E[gh][n2] = sigf(s.hob[gh][76 + n2]);
      s.A[gh][n2] = tanhf(s.hob[gh][108 + n2]);
    }

    // ---- read head addressing (pre-write M), then write head addressing ----
    address_head(g2a, n2, wave, lane, 0, &s.hob[g2a][0],  &s.wr[g2a][0],
                 &s.M[g2a][0][0], s);
    address_head(g2a, n2, wave, lane, 1, &s.hob[g2a][38], &s.ww[g2a][0],
                 &s.M[g2a][0][0], s);

    // ---- R = wr . M (pre-write M); 1024 threads, 16 chunks x 16 slots ----
    {
      const int gg  = tid >> 9;
      const int c16 = (tid >> 5) & 15;
      const int m   = tid & 31;
      const float* Mg = &s.M[gg][0][0];
      const int nb = c16 * 16;
      float acc = 0.0f;
      #pragma unroll 4
      for (int nn = 0; nn < 16; ++nn) {
        const int n = nb + nn;
        acc = fmaf(s.wr[gg][n], Mg[n*MPAD + m], acc);
      }
      s.rpart[gg][c16][m] = acc;
    }
    __syncthreads();
    if (tid < 512 && n2 < MU) {
      float r = 0.0f;
      #pragma unroll
      for (int c = 0; c < 16; ++c) r += s.rpart[gh][c][n2];
      s.R[gh][n2] = r;
    }
    __syncthreads();

    // ---- memory write: M = M*(1 - ww*E) + ww*A; 1024 threads, half-row each ----
    {
      const int gg   = tid >> 9;
      const int row  = tid & 255;
      const int half = (tid >> 8) & 1;
      const float wwn = s.ww[gg][row];
      float* Mr       = &s.M[gg][row][half*16];
      const float* Eg = &s.E[gg][half*16];
      const float* Ag = &s.A[gg][half*16];
      #pragma unroll
      for (int m = 0; m < 16; ++m) {
        Mr[m] = Mr[m] * (1.0f - wwn*Eg[m]) + wwn*Ag[m];
      }
    }

    // ---- output: Y = clip([R | h] @ out_W + b) ----
    if (tid < 512) {
      const int o = n2 >> 5;   // 0..7
      const int l = n2 & 31;
      float acc = 0.0f;
      #pragma unroll
      for (int ss = 0; ss < 9; ++ss) {
        const int j = l + 32*ss;     // covers 0..287 exactly
        float v = (j < 32) ? s.R[gh][j] : s.h[gh][j - 32];
        acc = fmaf(v, oW[j*8 + o], acc);
      }
      #pragma unroll
      for (int m = 16; m >= 1; m >>= 1) acc += __shfl_xor(acc, m, 64);
      if (l == 0) {
        float y = acc + ob[o];
        y = fminf(fmaxf(y, -20.0f), 20.0f);
        Y[((bB + gh)*TSTEPS + t)*8 + o] = y;
      }
    }
    __syncthreads();
  }
}

extern "C" void kernel_launch(void* const* d_in, const int* in_sizes, int n_in,
                              void* d_out, int out_size, void* d_ws, size_t ws_size,
                              hipStream_t stream)
{
  const float* X     = (const float*)d_in[0];
  const float* Wk    = (const float*)d_in[1];
  const float* Wr    = (const float*)d_in[2];
  const float* Lb    = (const float*)d_in[3];
  const float* rW    = (const float*)d_in[4];
  const float* rb    = (const float*)d_in[5];
  const float* wW    = (const float*)d_in[6];
  const float* wb    = (const float*)d_in[7];
  const float* oW    = (const float*)d_in[8];
  const float* ob    = (const float*)d_in[9];
  const float* rInit = (const float*)d_in[10];
  const float* wrI   = (const float*)d_in[11];
  const float* wwI   = (const float*)d_in[12];
  float* Y = (float*)d_out;

  hipLaunchKernelGGL(ntm_fused, dim3(256), dim3(1024), 0, stream,
                     X, Wk, Wr, Lb, rW, rb, wW, wb, oW, ob, rInit, wrI, wwI, Y);
}

// Round 4
// 2007.169 us; speedup vs baseline: 1.9738x; 1.9738x over previous
//
#include <hip/hip_runtime.h>
#include <math.h>

// Neural Turing Machine forward, fully fused persistent kernel.
// Grid: 256 blocks x 768 threads; each block owns G=2 batch elements and
// runs all T=64 steps with state in LDS. No inter-block communication.
//
// R3 lesson: 1024 threads -> __launch_bounds__(1024) caps VGPR at 64 ->
// z-GEMM spilled to scratch (WRITE_SIZE 1MB->96MB, FETCH 6MB->2.2GB, 2x
// slower). R4: 768 threads (12 waves/CU, 3/SIMD, VGPR cap ~168 -> no spill).
// Heavy GEMMs split 3-way over quarters q=tid>>8; light phases run on
// tid<512 with waves 8-11 idling through the barriers (guarded writes only).

#define NSLOT  256
#define MU     32
#define MPAD   33      // +1 pad: avoids 32-bank conflicts on M rows
#define TSTEPS 64
#define EPSF   1e-8f

__device__ __forceinline__ float sigf(float x){ return 1.0f/(1.0f + expf(-x)); }
__device__ __forceinline__ float softplusf_(float x){ return fmaxf(x,0.0f) + log1pf(expf(-fabsf(x))); }

__device__ __forceinline__ float wred_sum(float v){
  #pragma unroll
  for (int m = 32; m >= 1; m >>= 1) v += __shfl_xor(v, m, 64);
  return v;
}
__device__ __forceinline__ float wred_max(float v){
  #pragma unroll
  for (int m = 32; m >= 1; m >>= 1) v = fmaxf(v, __shfl_xor(v, m, 64));
  return v;
}

struct __align__(16) Smem {
  float M[2][NSLOT][MPAD];   // memory, padded rows              67.6 KB
  float zp[3][2][1024];      // z partials [quarter][g][col]     24   KB
  float h[2][256];           // 16B-aligned for float4 reads
  float c[2][256];
  float hob[2][140];         // [read ho(38) | write wo(102)]
  float xcat[2][40];         // [x(8) | R(32)], 16B-aligned
  float wr[2][NSLOT];        // read weights state
  float ww[2][NSLOT];        // write weights state
  float wg[2][2][NSLOT];     // shift-conv scratch [head][g][slot]
  float k[2][2][MU];         // key buffer [head][g][m]
  float E[2][MU];
  float A[2][MU];
  float R[2][MU];
  float hpart[3][2][140];    // head GEMM partials [quarter][g][col]
  float rpart[2][8][MU];     // read-vector partials [g][chunk][m]
  float red[3][16];          // per-site reduction buffers (12 waves)
};  // ~114 KB -> 1 block/CU

// Block-level reduction over batch-slot g2a (active threads: waves 0-3 g=0,
// waves 4-7 g=1). Waves 8-11 participate in barriers only; their red[] slots
// are written but never read. Caller passes a DISTINCT red buffer per site.
// ALL 768 threads must call.
__device__ __forceinline__ float grp_red_sum(float v, float* red, int wave, int lane, int g2a){
  v = wred_sum(v);
  if (lane == 0) red[wave] = v;
  __syncthreads();
  const int b = g2a*4;
  return red[b] + red[b+1] + red[b+2] + red[b+3];
}
__device__ __forceinline__ float grp_red_max(float v, float* red, int wave, int lane, int g2a){
  v = wred_max(v);
  if (lane == 0) red[wave] = v;
  __syncthreads();
  const int b = g2a*4;
  return fmaxf(fmaxf(red[b], red[b+1]), fmaxf(red[b+2], red[b+3]));
}

// NTM addressing for one head. Active threads (act=true, tid<512) own slot n2
// of batch-slot g2a; inactive threads flow through every barrier with writes
// suppressed. head = 0 (read) / 1 (write) selects private k/wg buffers.
__device__ void address_head(bool act, int g2a, int n2, int wave, int lane, int head,
                             const float* ho, float* wst, const float* Mg,
                             Smem& s)
{
  // per-head scalars, computed redundantly per thread (LDS broadcast reads)
  float beta  = softplusf_(ho[32]);
  float gg    = sigf(ho[33]);
  float r0 = ho[34], r1 = ho[35], r2 = ho[36];
  float m3 = fmaxf(r0, fmaxf(r1, r2));
  float e0 = expf(r0-m3), e1 = expf(r1-m3), e2 = expf(r2-m3);
  float inv3 = 1.0f/(e0+e1+e2);
  float s0 = e0*inv3, s1 = e1*inv3, s2 = e2*inv3;
  float gamma = 1.0f + softplusf_(ho[37]);

  float* kbuf  = &s.k[head][g2a][0];
  float* wgbuf = &s.wg[head][g2a][0];

  if (act && n2 < MU) kbuf[n2] = tanhf(ho[n2]);
  __syncthreads();

  float kn = 0.0f;
  #pragma unroll
  for (int m = 0; m < MU; ++m){ float kv = kbuf[m]; kn = fmaf(kv, kv, kn); }
  kn = sqrtf(kn);

  // cosine similarity for this thread's slot n2
  const float* Mr = Mg + n2*MPAD;
  float dot = 0.0f, mm = 0.0f;
  #pragma unroll
  for (int m = 0; m < MU; ++m){ float mv = Mr[m]; dot = fmaf(mv, kbuf[m], dot); mm = fmaf(mv, mv, mm); }
  float sim = dot / (sqrtf(mm)*kn + EPSF);

  // content softmax over 256 slots
  float bs = beta * sim;
  float mx = grp_red_max(bs, s.red[0], wave, lane, g2a);
  float ex = expf(bs - mx);
  float sm = grp_red_sum(ex, s.red[1], wave, lane, g2a);
  float wc = ex / sm;

  // interpolate with previous weights, publish for shift conv
  float wgv = fmaf(gg, wc, (1.0f - gg)*wst[n2]);
  if (act) wgbuf[n2] = wgv;
  __syncthreads();

  // circular shift conv: w_s[i] = s0*wg[i+1] + s1*wg[i] + s2*wg[i-1]
  float ws = s0*wgbuf[(n2+1)&255] + s1*wgbuf[n2] + s2*wgbuf[(n2-1)&255];

  // sharpen + normalize
  float wp = powf(ws, gamma);
  float sp = grp_red_sum(wp, s.red[2], wave, lane, g2a);
  if (act) wst[n2] = wp / (sp + EPSF);
}

__global__ __launch_bounds__(768)
void ntm_fused(const float* __restrict__ X,
               const float* __restrict__ Wk,   const float* __restrict__ Wr,
               const float* __restrict__ Lb,
               const float* __restrict__ rW,   const float* __restrict__ rb,
               const float* __restrict__ wW,   const float* __restrict__ wb,
               const float* __restrict__ oW,   const float* __restrict__ ob,
               const float* __restrict__ rInit,
               const float* __restrict__ wrI,  const float* __restrict__ wwI,
               float* __restrict__ Y)
{
  __shared__ Smem s;

  const int tid  = threadIdx.x;
  const int q    = tid >> 8;        // third 0..2 (k-split index for GEMMs)
  const int n2   = tid & 255;       // unit / slot / column-group index
  const int wave = tid >> 6;        // 0..11
  const int lane = tid & 63;
  const bool act = (tid < 512);     // active in 512-wide phases
  const int gh   = q & 1;           // batch slot for tid<512 phases (q==2 unused)
  const int g2a  = act ? (tid >> 8) : 0;  // batch slot for addressing
  const int bB   = blockIdx.x * 2;  // first batch element of this block

  // ---------------- init state (512 threads; no internal barriers) ----------------
  if (act) {
    for (int m = 0; m < MU; ++m) s.M[gh][n2][m] = 1e-6f;
    s.h[gh][n2] = 0.0f;
    s.c[gh][n2] = 0.0f;
    if (n2 < MU) s.R[gh][n2] = tanhf(rInit[n2]);
    // initial weight softmaxes (serial per thread, init-only, broadcast reads)
    float mx = -1e30f;
    for (int i = 0; i < NSLOT; ++i) mx = fmaxf(mx, wrI[i]);
    float sm = 0.0f;
    for (int i = 0; i < NSLOT; ++i) sm += expf(wrI[i] - mx);
    s.wr[gh][n2] = expf(wrI[n2] - mx) / sm;
    mx = -1e30f;
    for (int i = 0; i < NSLOT; ++i) mx = fmaxf(mx, wwI[i]);
    sm = 0.0f;
    for (int i = 0; i < NSLOT; ++i) sm += expf(wwI[i] - mx);
    s.ww[gh][n2] = expf(wwI[n2] - mx) / sm;
  }
  __syncthreads();

  // ---------------- time loop ----------------
  for (int t = 0; t < TSTEPS; ++t) {
    // x_cat = [x(8) | R(32)] for both batch slots
    if (act && n2 < 40) {
      s.xcat[gh][n2] = (n2 < 8) ? X[((bB + gh)*TSTEPS + t)*8 + n2]
                                : s.R[gh][n2 - 8];
    }
    __syncthreads();

    // ---- z = x_cat@Wk + h@Wr (+b in gate phase); 3-way k-split ----
    // q0: Wk rows 0..39 + Wr rows 0..59 (25 4-row bodies)
    // q1: Wr rows 60..159 (25)   q2: Wr rows 160..255 (24)
    {
      const int c0 = n2 * 4;
      float a0x=0.f,a0y=0.f,a0z=0.f,a0w=0.f;   // g=0
      float a1x=0.f,a1y=0.f,a1z=0.f,a1w=0.f;   // g=1
      if (q == 0) {
        #pragma unroll 2
        for (int i4 = 0; i4 < 10; ++i4) {
          const int r = i4*4;
          float4 x0 = *(const float4*)&s.xcat[0][r];
          float4 x1 = *(const float4*)&s.xcat[1][r];
          float4 w0 = *(const float4*)&Wk[(r+0)*1024 + c0];
          float4 w1 = *(const float4*)&Wk[(r+1)*1024 + c0];
          float4 w2 = *(const float4*)&Wk[(r+2)*1024 + c0];
          float4 w3 = *(const float4*)&Wk[(r+3)*1024 + c0];
          a0x=fmaf(w0.x,x0.x,a0x); a0y=fmaf(w0.y,x0.x,a0y); a0z=fmaf(w0.z,x0.x,a0z); a0w=fmaf(w0.w,x0.x,a0w);
          a1x=fmaf(w0.x,x1.x,a1x); a1y=fmaf(w0.y,x1.x,a1y); a1z=fmaf(w0.z,x1.x,a1z); a1w=fmaf(w0.w,x1.x,a1w);
          a0x=fmaf(w1.x,x0.y,a0x); a0y=fmaf(w1.y,x0.y,a0y); a0z=fmaf(w1.z,x0.y,a0z); a0w=fmaf(w1.w,x0.y,a0w);
          a1x=fmaf(w1.x,x1.y,a1x); a1y=fmaf(w1.y,x1.y,a1y); a1z=fmaf(w1.z,x1.y,a1z); a1w=fmaf(w1.w,x1.y,a1w);
          a0x=fmaf(w2.x,x0.z,a0x); a0y=fmaf(w2.y,x0.z,a0y); a0z=fmaf(w2.z,x0.z,a0z); a0w=fmaf(w2.w,x0.z,a0w);
          a1x=fmaf(w2.x,x1.z,a1x); a1y=fmaf(w2.y,x1.z,a1y); a1z=fmaf(w2.z,x1.z,a1z); a1w=fmaf(w2.w,x1.z,a1w);
          a0x=fmaf(w3.x,x0.w,a0x); a0y=fmaf(w3.y,x0.w,a0y); a0z=fmaf(w3.z,x0.w,a0z); a0w=fmaf(w3.w,x0.w,a0w);
          a1x=fmaf(w3.x,x1.w,a1x); a1y=fmaf(w3.y,x1.w,a1y); a1z=fmaf(w3.z,x1.w,a1z); a1w=fmaf(w3.w,x1.w,a1w);
        }
      }
      const int rlo = (q==0) ? 0 : (q==1 ? 60 : 160);
      const int rhi = (q==0) ? 60 : (q==1 ? 160 : 256);
      #pragma unroll 2
      for (int r = rlo; r < rhi; r += 4) {
        float4 h0 = *(const float4*)&s.h[0][r];
        float4 h1 = *(const float4*)&s.h[1][r];
        float4 w0 = *(const float4*)&Wr[(r+0)*1024 + c0];
        float4 w1 = *(const float4*)&Wr[(r+1)*1024 + c0];
        float4 w2 = *(const float4*)&Wr[(r+2)*1024 + c0];
        float4 w3 = *(const float4*)&Wr[(r+3)*1024 + c0];
        a0x=fmaf(w0.x,h0.x,a0x); a0y=fmaf(w0.y,h0.x,a0y); a0z=fmaf(w0.z,h0.x,a0z); a0w=fmaf(w0.w,h0.x,a0w);
        a1x=fmaf(w0.x,h1.x,a1x); a1y=fmaf(w0.y,h1.x,a1y); a1z=fmaf(w0.z,h1.x,a1z); a1w=fmaf(w0.w,h1.x,a1w);
        a0x=fmaf(w1.x,h0.y,a0x); a0y=fmaf(w1.y,h0.y,a0y); a0z=fmaf(w1.z,h0.y,a0z); a0w=fmaf(w1.w,h0.y,a0w);
        a1x=fmaf(w1.x,h1.y,a1x); a1y=fmaf(w1.y,h1.y,a1y); a1z=fmaf(w1.z,h1.y,a1z); a1w=fmaf(w1.w,h1.y,a1w);
        a0x=fmaf(w2.x,h0.z,a0x); a0y=fmaf(w2.y,h0.z,a0y); a0z=fmaf(w2.z,h0.z,a0z); a0w=fmaf(w2.w,h0.z,a0w);
        a1x=fmaf(w2.x,h1.z,a1x); a1y=fmaf(w2.y,h1.z,a1y); a1z=fmaf(w2.z,h1.z,a1z); a1w=fmaf(w2.w,h1.z,a1w);
        a0x=fmaf(w3.x,h0.w,a0x); a0y=fmaf(w3.y,h0.w,a0y); a0z=fmaf(w3.z,h0.w,a0z); a0w=fmaf(w3.w,h0.w,a0w);
        a1x=fmaf(w3.x,h1.w,a1x); a1y=fmaf(w3.y,h1.w,a1y); a1z=fmaf(w3.z,h1.w,a1z); a1w=fmaf(w3.w,h1.w,a1w);
      }
      *(float4*)&s.zp[q][0][c0] = make_float4(a0x,a0y,a0z,a0w);
      *(float4*)&s.zp[q][1][c0] = make_float4(a1x,a1y,a1z,a1w);
    }
    __syncthreads();

    // ---- LSTM gates (keras order i,f,g,o); Z==h since |h|<1<CLIP ----
    if (act) {
      float zi = s.zp[0][gh][n2      ]+s.zp[1][gh][n2      ]+s.zp[2][gh][n2      ] + Lb[n2      ];
      float zf = s.zp[0][gh][n2 + 256]+s.zp[1][gh][n2 + 256]+s.zp[2][gh][n2 + 256] + Lb[n2 + 256];
      float zg = s.zp[0][gh][n2 + 512]+s.zp[1][gh][n2 + 512]+s.zp[2][gh][n2 + 512] + Lb[n2 + 512];
      float zo = s.zp[0][gh][n2 + 768]+s.zp[1][gh][n2 + 768]+s.zp[2][gh][n2 + 768] + Lb[n2 + 768];
      float cn = sigf(zf)*s.c[gh][n2] + sigf(zi)*tanhf(zg);
      float hn = sigf(zo)*tanhf(cn);
      s.c[gh][n2] = cn;
      s.h[gh][n2] = hn;
    }
    __syncthreads();

    // ---- head outputs: ho = h @ [read_W | write_W]; 3-way k-split ----
    // q0: rows 0..87, q1: 88..171, q2: 172..255 (4-row bodies)
    if (n2 < 140) {
      const float* Wp; int stride, cc;
      if (n2 < 38) { Wp = rW; stride = 38;  cc = n2; }
      else         { Wp = wW; stride = 102; cc = n2 - 38; }
      const int i0 = (q==0) ? 0 : (q==1 ? 88 : 172);
      const int i1 = (q==0) ? 88 : (q==1 ? 172 : 256);
      float acc0 = 0.0f, acc1 = 0.0f;
      #pragma unroll 2
      for (int r = i0; r < i1; r += 4) {
        float4 h0 = *(const float4*)&s.h[0][r];
        float4 h1 = *(const float4*)&s.h[1][r];
        float wv0 = Wp[(r+0)*stride + cc];
        float wv1 = Wp[(r+1)*stride + cc];
        float wv2 = Wp[(r+2)*stride + cc];
        float wv3 = Wp[(r+3)*stride + cc];
        acc0 = fmaf(wv0, h0.x, acc0); acc1 = fmaf(wv0, h1.x, acc1);
        acc0 = fmaf(wv1, h0.y, acc0); acc1 = fmaf(wv1, h1.y, acc1);
        acc0 = fmaf(wv2, h0.z, acc0); acc1 = fmaf(wv2, h1.z, acc1);
        acc0 = fmaf(wv3, h0.w, acc0); acc1 = fmaf(wv3, h1.w, acc1);
      }
      s.hpart[q][0][n2] = acc0;
      s.hpart[q][1][n2] = acc1;
    }
    __syncthreads();
    if (act && n2 < 140) {
      float bias = (n2 < 38) ? rb[n2] : wb[n2 - 38];
      s.hob[gh][n2] = s.hpart[0][gh][n2] + s.hpart[1][gh][n2]
                    + s.hpart[2][gh][n2] + bias;
    }
    __syncthreads();

    // erase / add vectors (write head raw outputs wo[38:70], wo[70:102])
    if (act && n2 < MU) {
      s.E[gh][n2] = sigf(s.hob[gh][76 + n2]);
      s.A[gh][n2] = tanhf(s.hob[gh][108 + n2]);
    }

    // ---- read head addressing (pre-write M), then write head addressing ----
    address_head(act, g2a, n2, wave, lane, 0, &s.hob[g2a][0],  &s.wr[g2a][0],
                 &s.M[g2a][0][0], s);
    address_head(act, g2a, n2, wave, lane, 1, &s.hob[g2a][38], &s.ww[g2a][0],
                 &s.M[g2a][0][0], s);

    // ---- R = wr . M (pre-write M); 512 threads, 8 chunks x 32 slots ----
    if (act) {
      const int chunk = n2 >> 5;
      const int m     = n2 & 31;
      const float* Mg = &s.M[gh][0][0];
      const int nb = chunk * 32;
      float acc = 0.0f;
      #pragma unroll 4
      for (int nn = 0; nn < 32; ++nn) {
        const int n = nb + nn;
        acc = fmaf(s.wr[gh][n], Mg[n*MPAD + m], acc);
      }
      s.rpart[gh][chunk][m] = acc;
    }
    __syncthreads();
    if (act && n2 < MU) {
      float r = 0.0f;
      #pragma unroll
      for (int c = 0; c < 8; ++c) r += s.rpart[gh][c][n2];
      s.R[gh][n2] = r;
    }
    __syncthreads();

    // ---- memory write: M = M*(1 - ww*E) + ww*A (thread owns slot n2) ----
    if (act) {
      const float wwn = s.ww[gh][n2];
      float* Mr = &s.M[gh][n2][0];
      #pragma unroll
      for (int m = 0; m < MU; ++m) {
        Mr[m] = Mr[m] * (1.0f - wwn*s.E[gh][m]) + wwn*s.A[gh][m];
      }
    }

    // ---- output: Y = clip([R | h] @ out_W + b) ----
    if (act) {
      const int o = n2 >> 5;   // 0..7
      const int l = n2 & 31;
      float acc = 0.0f;
      #pragma unroll
      for (int ss = 0; ss < 9; ++ss) {
        const int j = l + 32*ss;     // covers 0..287 exactly
        float v = (j < 32) ? s.R[gh][j] : s.h[gh][j - 32];
        acc = fmaf(v, oW[j*8 + o], acc);
      }
      #pragma unroll
      for (int m = 16; m >= 1; m >>= 1) acc += __shfl_xor(acc, m, 64);
      if (l == 0) {
        float y = acc + ob[o];
        y = fminf(fmaxf(y, -20.0f), 20.0f);
        Y[((bB + gh)*TSTEPS + t)*8 + o] = y;
      }
    }
    __syncthreads();
  }
}

extern "C" void kernel_launch(void* const* d_in, const int* in_sizes, int n_in,
                              void* d_out, int out_size, void* d_ws, size_t ws_size,
                              hipStream_t stream)
{
  const float* X     = (const float*)d_in[0];
  const float* Wk    = (const float*)d_in[1];
  const float* Wr    = (const float*)d_in[2];
  const float* Lb    = (const float*)d_in[3];
  const float* rW    = (const float*)d_in[4];
  const float* rb    = (const float*)d_in[5];
  const float* wW    = (const float*)d_in[6];
  const float* wb    = (const float*)d_in[7];
  const float* oW    = (const float*)d_in[8];
  const float* ob    = (const float*)d_in[9];
  const float* rInit = (const float*)d_in[10];
  const float* wrI   = (const float*)d_in[11];
  const float* wwI   = (const float*)d_in[12];
  float* Y = (float*)d_out;

  hipLaunchKernelGGL(ntm_fused, dim3(256), dim3(768), 0, stream,
                     X, Wk, Wr, Lb, rW, rb, wW, wb, oW, ob, rInit, wrI, wwI, Y);
}